// Round 6
// baseline (292.882 us; speedup 1.0000x reference)
//
#include <hip/hip_runtime.h>
#include <math.h>

#define ZDIM  128
#define ODIM  16
#define INDIM 274
#define TJ    32
#define GCOEFF (-2016.125f)
#define DMAX  2.25f
#define GDELTA (2.0f / 127.0f)

// workspace layout (float offsets)
#define OFF_TABP  0        // 128*8  {sg1,sg2,sb1,sb2,w144_1,w144_2,0,0}
#define OFF_FDOP  1024     // 4*128*2 paired
#define OFF_W3HI  2048     // 2048 ushort = 1024 floats (B-frag order)
#define OFF_W3LO  3072     // 1024 floats
#define OFF_FDSUM 4096     // 4
#define OFF_FDSQ  4100     // 4
#define OFF_RR    4104     // 4*N*3 = 4608
#define OFF_BHI   8720     // 32768 ushort (rpe-GEMM B frags hi)
#define OFF_BLO   25104    // 32768 ushort
#define OFF_CWGP  41488    // 128*256 fp32 paired cols [g][2q|2q+1]

// Bijective swizzled s_tab index. Round-4/5 bug: q*8+((q>>3)&3)*4 overlaps at
// q=31/32 etc. (swizzle term wraps 12->0 while base advances only 8) -> two
// lanes ds_write_b128 the same LDS words -> sg/w144 corruption -> y += d*0.33
// -> absmax ~0.7. The (q>>5)*16 gap makes it injective; lg-groups stay 68
// floats apart (banks +4) so broadcast reads remain conflict-free.
#define TABIDX(q) ((q) * 8 + ((q) >> 5) * 16 + (((q) >> 3) & 3) * 4)

typedef __attribute__((ext_vector_type(8))) short bf16x8;
typedef __attribute__((ext_vector_type(4))) float f32x4;
#define MFMA_BF16 __builtin_amdgcn_mfma_f32_16x16x32_bf16

static __device__ inline ushort f2bf(float x) {
  union { float f; unsigned u; } v; v.f = x;
  unsigned r = v.u + 0x7fffu + ((v.u >> 16) & 1u);
  return (ushort)(r >> 16);
}
static __device__ inline float bf2f(ushort h) {
  union { unsigned u; float f; } v; v.u = ((unsigned)h) << 16;
  return v.f;
}
static __device__ inline void cvt8(float4 a, float4 b, bf16x8& hi, bf16x8& lo) {
  float v[8] = {a.x, a.y, a.z, a.w, b.x, b.y, b.z, b.w};
#pragma unroll
  for (int e = 0; e < 8; ++e) {
    ushort h = f2bf(v[e]);
    hi[e] = (short)h;
    lo[e] = (short)f2bf(v[e] - bf2f(h));
  }
}

// Fused preprocessing:
//  blocks 0..263  : B-fragment fills (rpe-GEMM bf16 hi/lo, cwg paired, W3 frags)
//  block  264     : scalar tables (fd, sg/sb, fdop, fdsum)
//  blocks 265..   : r_repr (one wave per (bm,n))
__global__ __launch_bounds__(256) void k0_all(
    const float* __restrict__ nf, const float* __restrict__ Wf,
    const float* __restrict__ gamma, const float* __restrict__ beta,
    const float* __restrict__ W1, const float* __restrict__ W2,
    const float* __restrict__ W3, const float* __restrict__ ttra,
    const float* __restrict__ rn, float* __restrict__ ws, int N, int A) {
  const int blk = blockIdx.x;
  const int t = threadIdx.x;

  if (blk < 264) {
    const int flat = blk * 256 + t;
    if (flat < 32768) {
      // rpe-GEMM B frags: value = gamma[146+z]*W[q][146+z], paired col order
      int e = flat & 7, l = (flat >> 3) & 63, ct = (flat >> 9) & 15, kt = flat >> 13;
      int z = kt * 32 + (l >> 4) * 8 + e;
      int n = ct * 16 + (l & 15);
      int q = n >> 1;
      const float* row = (n & 1) ? (W2 + (size_t)q * INDIM) : (W1 + (size_t)q * INDIM);
      float v = gamma[146 + z] * row[146 + z];
      ushort h = f2bf(v);
      ushort lo = f2bf(v - bf2f(h));
      ((ushort*)(ws + OFF_BHI))[flat] = h;
      ((ushort*)(ws + OFF_BLO))[flat] = lo;
    } else if (flat < 65536) {
      int c = flat - 32768;
      int g = c >> 8, n = c & 255, q = n >> 1;
      const float* row = (n & 1) ? (W2 + (size_t)q * INDIM) : (W1 + (size_t)q * INDIM);
      ws[OFF_CWGP + g * 256 + n] = gamma[16 + g] * row[16 + g];
    } else if (flat < 67584) {
      // W3 B-frags: B[k=q][col=o], k = kt*32 + (l>>4)*8 + e
      int f = flat - 65536;  // 0..2047
      int e = f & 7, l = (f >> 3) & 63, kt = (f >> 9) & 3;
      int o = l & 15;
      int q = kt * 32 + (l >> 4) * 8 + e;
      float v = W3[o * 128 + q];
      ushort h = f2bf(v);
      ushort lo = f2bf(v - bf2f(h));
      ((ushort*)(ws + OFF_W3HI))[f] = h;
      ((ushort*)(ws + OFF_W3LO))[f] = lo;
    }
    return;
  }

  if (blk == 264) {
    __shared__ float fd[64];
    if (t < 64) {
      int bm = t >> 4, c = t & 15;
      const float4* a4 = (const float4*)(nf + bm * 256);
      const float4* b4 = (const float4*)(Wf + c * 256);
      float s = 0.f;
      for (int f = 0; f < 64; ++f) {
        float4 a = a4[f], b = b4[f];
        s += a.x * b.x + a.y * b.y + a.z * b.z + a.w * b.w;
      }
      fd[t] = s;
    }
    __syncthreads();
    {
      int q = t & 127, which = t >> 7;
      const float* r = which ? (W2 + (size_t)q * INDIM) : (W1 + (size_t)q * INDIM);
      float sg = 0.f, sb = 0.f;
      for (int c = 0; c < INDIM; ++c) { sg += gamma[c] * r[c]; sb += beta[c] * r[c]; }
      float* tp = ws + OFF_TABP + q * 8;
      tp[0 + which] = sg;
      tp[2 + which] = sb;
      tp[4 + which] = gamma[144] * r[144];
      if (!which) { tp[6] = 0.f; tp[7] = 0.f; }
      for (int bm = 0; bm < 4; ++bm) {
        float f1 = 0.f;
        for (int c = 0; c < 16; ++c) f1 += fd[bm * 16 + c] * gamma[c] * r[c];
        ws[OFF_FDOP + (bm * 128 + q) * 2 + which] = f1;
      }
    }
    if (t < 4) {
      float s = 0.f, q = 0.f;
      for (int c = 0; c < 16; ++c) { float v = fd[t * 16 + c]; s += v; q += v * v; }
      ws[OFF_FDSUM + t] = s;
      ws[OFF_FDSQ + t] = q;
    }
    return;
  }

  // r_repr: wave w of block handles flat = (blk-265)*4 + w
  {
    int w = t >> 6, lane = t & 63;
    int flat = (blk - 265) * 4 + w;
    if (flat >= 4 * N) return;
    int bm = flat / N, n = flat - bm * N;
    float a0 = 0.f, a1 = 0.f, a2 = 0.f;
    for (int a = lane; a < A; a += 64) {
      float wv = ttra[(size_t)n * A + a];
      const float* rp = rn + ((size_t)bm * A + a) * 3;
      a0 += wv * rp[0]; a1 += wv * rp[1]; a2 += wv * rp[2];
    }
    for (int s = 32; s; s >>= 1) {
      a0 += __shfl_down(a0, s); a1 += __shfl_down(a1, s); a2 += __shfl_down(a2, s);
    }
    if (lane == 0) {
      float* o = ws + OFF_RR + ((size_t)bm * N + n) * 3;
      o[0] = a0; o[1] = a1; o[2] = a2;
    }
  }
}

__global__ __launch_bounds__(256, 5) void k2_main(
    const float* __restrict__ rpe, const float* __restrict__ ws,
    float* __restrict__ out, int N) {
  const int t = threadIdx.x;
  const int njt = N / TJ;
  const int i = blockIdx.x / njt;
  const int j0 = (blockIdx.x % njt) * TJ;

  __shared__ ushort s_rdotb[32 * 258];  // bf16 rdot, paired cols, stride 258
  __shared__ float s_tab[1088];         // bijective swizzle, see TABIDX
  __shared__ float s_fdop[4 * 258];
  __shared__ float s_rsum[32], s_rsq[32];
  __shared__ float s_d[128];
  __shared__ float s_fdsum[4], s_fdsq[4];

  // --- stage tables ---
  if (t < 128) {
    int q = t;
    const float4* src = (const float4*)(ws + OFF_TABP + q * 8);
    float4* dst = (float4*)(s_tab + TABIDX(q));
    dst[0] = src[0];
    dst[1] = src[1];
  }
  for (int idx = t; idx < 1024; idx += 256) {
    int bm = idx >> 8, r = idx & 255;
    s_fdop[bm * 258 + r] = ws[OFF_FDOP + idx];
  }
  if (t < 4) { s_fdsum[t] = ws[OFF_FDSUM + t]; s_fdsq[t] = ws[OFF_FDSQ + t]; }

  // --- distances ---
  if (t < 128) {
    int bm = t >> 5, p = t & 31;
    const float* rr = ws + OFF_RR;
    const float* ri = rr + ((size_t)bm * N + i) * 3;
    const float* rj = rr + ((size_t)bm * N + j0 + p) * 3;
    float dx = ri[0] - rj[0], dy = ri[1] - rj[1], dz = ri[2] - rj[2];
    float sq = dx * dx + dy * dy + dz * dz;
    s_d[t] = sq > 0.f ? sqrtf(sq) : 0.f;
  }
  // --- rpe row sums (4 threads per row) ---
  if (t < 128) {
    int p = t >> 2, seg = t & 3;
    const float* row = rpe + ((size_t)(i * N) + j0 + p) * ZDIM + seg * 32;
    float s = 0.f, q = 0.f;
    for (int u = 0; u < 32; u += 4) {
      float4 v = *(const float4*)(row + u);
      s += v.x + v.y + v.z + v.w;
      q += v.x * v.x + v.y * v.y + v.z * v.z + v.w * v.w;
    }
    s += __shfl_xor(s, 1); q += __shfl_xor(q, 1);
    s += __shfl_xor(s, 2); q += __shfl_xor(q, 2);
    if (seg == 0) { s_rsum[p] = s; s_rsq[p] = q; }
  }

  // --- MFMA GEMM: rdot[32 rows][256 paired cols] ---
  {
    const int w = t >> 6, l = t & 63, lm = l & 15, lk = l >> 4;
    f32x4 acc[2][4];
#pragma unroll
    for (int mt = 0; mt < 2; ++mt)
#pragma unroll
      for (int nt = 0; nt < 4; ++nt) acc[mt][nt] = (f32x4){0.f, 0.f, 0.f, 0.f};
    const float* a0p = rpe + ((size_t)(i * N) + j0 + lm) * ZDIM;
    const float* a1p = a0p + 16 * ZDIM;
    const ushort* bhip = (const ushort*)(ws + OFF_BHI);
    const ushort* blop = (const ushort*)(ws + OFF_BLO);
#pragma unroll
    for (int kt = 0; kt < 4; ++kt) {
      const int ko = kt * 32 + lk * 8;
      bf16x8 ah0, al0, ah1, al1;
      cvt8(*(const float4*)(a0p + ko), *(const float4*)(a0p + ko + 4), ah0, al0);
      cvt8(*(const float4*)(a1p + ko), *(const float4*)(a1p + ko + 4), ah1, al1);
#pragma unroll
      for (int nt = 0; nt < 4; ++nt) {
        const size_t fo = (((size_t)kt * 16 + w * 4 + nt) * 64 + l) * 8;
        bf16x8 bh = *(const bf16x8*)(bhip + fo);
        bf16x8 bl = *(const bf16x8*)(blop + fo);
        acc[0][nt] = MFMA_BF16(ah0, bh, acc[0][nt], 0, 0, 0);
        acc[0][nt] = MFMA_BF16(al0, bh, acc[0][nt], 0, 0, 0);
        acc[0][nt] = MFMA_BF16(ah0, bl, acc[0][nt], 0, 0, 0);
        acc[1][nt] = MFMA_BF16(ah1, bh, acc[1][nt], 0, 0, 0);
        acc[1][nt] = MFMA_BF16(al1, bh, acc[1][nt], 0, 0, 0);
        acc[1][nt] = MFMA_BF16(ah1, bl, acc[1][nt], 0, 0, 0);
      }
    }
#pragma unroll
    for (int mt = 0; mt < 2; ++mt)
#pragma unroll
      for (int nt = 0; nt < 4; ++nt)
#pragma unroll
        for (int r = 0; r < 4; ++r) {
          int m = mt * 16 + lk * 4 + r;
          int n = w * 64 + nt * 16 + lm;
          s_rdotb[m * 258 + n] = f2bf(acc[mt][nt][r]);
        }
  }
  __syncthreads();

  // --- epilogue: hv computed in A-frag layout, x W3 via MFMA ---
  {
    const int w = t >> 6, l = t & 63, lm = l & 15, lg = l >> 4;
    const ushort* w3h = (const ushort*)(ws + OFF_W3HI);
    const ushort* w3l = (const ushort*)(ws + OFF_W3LO);
    const float2* cw2 = (const float2*)(ws + OFF_CWGP);
#pragma unroll
    for (int mt = 0; mt < 2; ++mt) {
      const int m0 = (w * 2 + mt) * 16;
      const int inst = m0 + lm;
      const int bm = inst >> 5, p = inst & 31;
      const float d = s_d[inst];
      // gauss window (rare): 8 offsets centered at d; beyond |d-off|>4*delta exp underflows
      float e8[8];
      float gsum = 0.f, gsq = 0.f;
      int g0 = 0;
      const bool needG = d < DMAX;
      const bool anyG = __any(needG) != 0;
      if (anyG) {
#pragma unroll
        for (int u = 0; u < 8; ++u) e8[u] = 0.f;
        if (needG) {
          g0 = (int)(d * 63.5f + 0.5f) - 4;
          g0 = g0 < 0 ? 0 : (g0 > 120 ? 120 : g0);
#pragma unroll
          for (int u = 0; u < 8; ++u) {
            float off = (float)(g0 + u) * GDELTA;
            float df = d - off;
            float e = __expf(GCOEFF * df * df);
            e8[u] = e; gsum += e; gsq += e * e;
          }
        }
      }
      const float inv = 1.0f / 274.0f;
      float xsum = s_fdsum[bm] + gsum + d + s_rsum[p];
      float xsq = s_fdsq[bm] + gsq + d * d + s_rsq[p];
      float mu = xsum * inv;
      float var = xsq * inv - mu * mu;
      float rs = rsqrtf(var + 1e-5f);
      float cc = rs * mu;
      f32x4 acc = {0.f, 0.f, 0.f, 0.f};
      const ushort* rrow = s_rdotb + p * 258;
      const float* fdo = s_fdop + bm * 258;
#pragma unroll
      for (int kt = 0; kt < 4; ++kt) {
        float hv[8];
#pragma unroll
        for (int e = 0; e < 8; ++e) {
          const int q = kt * 32 + lg * 8 + e;
          unsigned u = *(const unsigned*)(rrow + 2 * q);
          float r1 = __uint_as_float(u << 16);
          float r2 = __uint_as_float(u & 0xffff0000u);
          const float* tp = s_tab + TABIDX(q);
          float4 tv = *(const float4*)tp;
          float2 wv = *(const float2*)(tp + 4);
          float2 fv = *(const float2*)(fdo + 2 * q);
          float y1 = fmaf(d, wv.x, r1 + fv.x);
          float y2 = fmaf(d, wv.y, r2 + fv.y);
          if (anyG) {
            if (needG) {
              const float2* cb = cw2 + (size_t)g0 * 128 + q;
#pragma unroll
              for (int u2 = 0; u2 < 8; ++u2) {
                float2 cw = cb[(size_t)u2 * 128];
                y1 = fmaf(e8[u2], cw.x, y1);
                y2 = fmaf(e8[u2], cw.y, y2);
              }
            }
          }
          float a1 = fmaf(rs, y1, fmaf(-cc, tv.x, tv.z));
          float a2 = fmaf(rs, y2, fmaf(-cc, tv.y, tv.w));
          float sig = 1.0f / (1.0f + __expf(-a1));
          hv[e] = a1 * sig * a2;
        }
        bf16x8 Ahi, Alo;
        cvt8(*(float4*)&hv[0], *(float4*)&hv[4], Ahi, Alo);
        bf16x8 Bhi = *(const bf16x8*)(w3h + (kt * 64 + l) * 8);
        bf16x8 Blo = *(const bf16x8*)(w3l + (kt * 64 + l) * 8);
        acc = MFMA_BF16(Ahi, Bhi, acc, 0, 0, 0);
        acc = MFMA_BF16(Alo, Bhi, acc, 0, 0, 0);
        acc = MFMA_BF16(Ahi, Blo, acc, 0, 0, 0);
      }
      // C layout: col = lane&15 (= o), row = (lane>>4)*4 + r (= inst-in-tile)
#pragma unroll
      for (int r = 0; r < 4; ++r) {
        int io = m0 + lg * 4 + r;
        int bmo = io >> 5, po = io & 31;
        out[(((size_t)bmo * ODIM + lm) * N + i) * N + j0 + po] = acc[r];
      }
    }
  }
}

extern "C" void kernel_launch(void* const* d_in, const int* in_sizes, int n_in,
                              void* d_out, int out_size, void* d_ws, size_t ws_size,
                              hipStream_t stream) {
  const float* nf = (const float*)d_in[0];
  const float* rn = (const float*)d_in[1];
  const float* rpe = (const float*)d_in[2];
  const float* ttra = (const float*)d_in[3];
  const float* Wf = (const float*)d_in[4];
  const float* gamma = (const float*)d_in[5];
  const float* beta = (const float*)d_in[6];
  const float* W1 = (const float*)d_in[7];
  const float* W2 = (const float*)d_in[8];
  const float* W3 = (const float*)d_in[9];
  float* out = (float*)d_out;
  float* ws = (float*)d_ws;

  const int BM = in_sizes[0] / 256;       // 4
  const int A = in_sizes[1] / (3 * BM);   // 1536
  const int N = in_sizes[3] / A;          // 384

  k0_all<<<265 + N, 256, 0, stream>>>(nf, Wf, gamma, beta, W1, W2, W3,
                                      ttra, rn, ws, N, A);
  k2_main<<<N * (N / TJ), 256, 0, stream>>>(rpe, ws, out, N);
}